// Round 5
// baseline (275.630 us; speedup 1.0000x reference)
//
#include <hip/hip_runtime.h>
#include <hip/hip_bf16.h>

typedef __attribute__((ext_vector_type(4)))  float  f32x4;
typedef __attribute__((ext_vector_type(16))) float  f32x16;
typedef __attribute__((ext_vector_type(8)))  __bf16 bf16x8;
typedef __attribute__((ext_vector_type(4)))  __bf16 bf16x4;
typedef unsigned int u32x2 __attribute__((ext_vector_type(2)));
typedef unsigned int u32x4 __attribute__((ext_vector_type(4)));

#define LOG2E_O16 0.09016844005556021f  // log2(e)/16  (scale = 1/sqrt(256))

__device__ __forceinline__ void gload_lds16(const void* g, void* l) {
  __builtin_amdgcn_global_load_lds(
      (const __attribute__((address_space(1))) void*)g,
      (__attribute__((address_space(3))) void*)l, 16, 0, 0);
}

__device__ __forceinline__ void pl32swap(unsigned int& a, unsigned int& b) {
  u32x2 r = __builtin_amdgcn_permlane32_swap(a, b, false, false);
  a = r[0]; b = r[1];
}

__device__ __forceinline__ unsigned int pack2bf(float a, float b) {
  unsigned short ua = __builtin_bit_cast(unsigned short, (__bf16)a);
  unsigned short ub = __builtin_bit_cast(unsigned short, (__bf16)b);
  return (unsigned int)ua | ((unsigned int)ub << 16);
}

// ---------------- X = GA[g,n] * rep_R, fp32 -> bf16 ----------------
__global__ __launch_bounds__(256) void scale_kernel(
    const float* __restrict__ rep, const float* __restrict__ GA, __bf16* __restrict__ X)
{
  size_t i = (size_t)blockIdx.x * 256 + threadIdx.x;
  size_t e = i * 4;
  f32x4 r = *(const f32x4*)(rep + e);
  int dn = (int)(e >> 8);
  int n  = dn & 511;
  int g  = (dn >> 9) & 15;
  float ga = GA[g * 512 + n];
  bf16x4 o;
  o[0] = (__bf16)(r[0] * ga); o[1] = (__bf16)(r[1] * ga);
  o[2] = (__bf16)(r[2] * ga); o[3] = (__bf16)(r[3] * ga);
  *(bf16x4*)(X + e) = o;
}

// ---------------- weight convert: ten 256x256 fp32 w[K][N] -> bf16 wT[N][K] ----------------
struct WPtrs { const float* w[10]; };
__global__ __launch_bounds__(256) void wconv_kernel(WPtrs ws, __bf16* __restrict__ out)
{
  __shared__ float t[64][65];
  const float* w = ws.w[blockIdx.y];
  __bf16* o = out + (size_t)blockIdx.y * 65536;
  const int tr = (blockIdx.x & 3) * 64, tc = (blockIdx.x >> 2) * 64;
  const int r4 = threadIdx.x >> 6, c = threadIdx.x & 63;
#pragma unroll
  for (int p = 0; p < 16; ++p) {
    int row = p * 4 + r4;
    t[row][c] = w[(size_t)(tr + row) * 256 + tc + c];
  }
  __syncthreads();
#pragma unroll
  for (int p = 0; p < 16; ++p) {
    int row = p * 4 + r4;
    o[(size_t)(tc + row) * 256 + tr + c] = (__bf16)t[c][row];
  }
}

// ======== shared BK=64 tile body for the big GEMMs (128x128 tile, 4 waves) ========
#define GEMM64_BODY(A_, B_, bmv, bnv, Kv)                                          \
  f32x4 acc[4][4] = {};                                                            \
  for (int k0 = 0; k0 < (Kv); k0 += 64) {                                          \
    _Pragma("unroll")                                                              \
    for (int r = 0; r < 4; ++r) {                                                  \
      int rowl = r * 32 + (tid >> 3);                                              \
      int sl = (tid & 7) ^ (rowl & 7);                                             \
      gload_lds16((const char*)((A_) + (size_t)((bmv) + rowl) * (Kv) + k0) + sl * 16, \
                  (char*)sA + r * 4096 + wv * 1024);                               \
      gload_lds16((const char*)((B_) + (size_t)((bnv) + rowl) * (Kv) + k0) + sl * 16, \
                  (char*)sB + r * 4096 + wv * 1024);                               \
    }                                                                              \
    __syncthreads();                                                               \
    bf16x8 af[4][2], bfr[4][2];                                                    \
    _Pragma("unroll")                                                              \
    for (int mi = 0; mi < 4; ++mi) {                                               \
      int row = wr + mi * 16 + l16;                                                \
      _Pragma("unroll")                                                            \
      for (int kk = 0; kk < 2; ++kk) {                                             \
        int sl = (kk * 4 + lg) ^ (row & 7);                                        \
        af[mi][kk] = *(const bf16x8*)((const char*)sA + row * 128 + sl * 16);      \
      }                                                                            \
    }                                                                              \
    _Pragma("unroll")                                                              \
    for (int ni = 0; ni < 4; ++ni) {                                               \
      int row = wc + ni * 16 + l16;                                                \
      _Pragma("unroll")                                                            \
      for (int kk = 0; kk < 2; ++kk) {                                             \
        int sl = (kk * 4 + lg) ^ (row & 7);                                        \
        bfr[ni][kk] = *(const bf16x8*)((const char*)sB + row * 128 + sl * 16);     \
      }                                                                            \
    }                                                                              \
    _Pragma("unroll")                                                              \
    for (int kk = 0; kk < 2; ++kk)                                                 \
      _Pragma("unroll")                                                            \
      for (int mi = 0; mi < 4; ++mi)                                               \
        _Pragma("unroll")                                                          \
        for (int ni = 0; ni < 4; ++ni)                                             \
          acc[mi][ni] = __builtin_amdgcn_mfma_f32_16x16x32_bf16(                   \
              af[mi][kk], bfr[ni][kk], acc[mi][ni], 0, 0, 0);                      \
    __syncthreads();                                                               \
  }

// ---------------- fused multi-output GEMM: out[j] = A @ Bt[j]^T + bias[j] ----------------
struct QKV3 {
  const __bf16* Bt[3];
  const float* bias[3];
  __bf16* out[3];
};

template<int NW>
__global__ __launch_bounds__(256) void gemmqkv_kernel(
    const __bf16* __restrict__ A, QKV3 args, int K)
{
  __shared__ __align__(16) __bf16 sA[128 * 64];
  __shared__ __align__(16) __bf16 sB[128 * 64];
  const int tid = threadIdx.x, lane = tid & 63, wv = tid >> 6;
  const int l16 = lane & 15, lg = lane >> 4;
  const int wr = (wv >> 1) * 64, wc = (wv & 1) * 64;

  const int nblk = gridDim.x, cpx = nblk >> 3, orig = blockIdx.x;
  const int wg  = (orig & 7) * cpx + (orig >> 3);       // bijective XCD swizzle
  const int r_  = wg / (2 * NW), rem = wg % (2 * NW);
  const int j   = rem >> 1;
  const int bm  = r_ * 128, bn = (rem & 1) * 128;
  const __bf16* __restrict__ Bt = args.Bt[j];

  GEMM64_BODY(A, Bt, bm, bn, K)

  const float* bias = args.bias[j];
  __bf16* C = args.out[j];
#pragma unroll
  for (int mi = 0; mi < 4; ++mi)
#pragma unroll
    for (int ni = 0; ni < 4; ++ni) {
      int col = bn + wc + ni * 16 + l16;
      float bval = bias[col];
      int row0 = bm + wr + mi * 16 + lg * 4;
#pragma unroll
      for (int i = 0; i < 4; ++i)
        C[(size_t)(row0 + i) * 256 + col] = (__bf16)(acc[mi][ni][i] + bval);
    }
}

// ---------------- O-proj GEMM: C = R + relu(A @ Bt^T + bias) ----------------
__global__ __launch_bounds__(256) void gemm128_kernel(
    const __bf16* __restrict__ A, const __bf16* __restrict__ Bt,
    const float* __restrict__ bias, const __bf16* __restrict__ R,
    __bf16* __restrict__ C, int K)
{
  __shared__ __align__(16) __bf16 sA[128 * 64];
  __shared__ __align__(16) __bf16 sB[128 * 64];
  const int tid = threadIdx.x, lane = tid & 63, wv = tid >> 6;
  const int l16 = lane & 15, lg = lane >> 4;
  const int wr = (wv >> 1) * 64, wc = (wv & 1) * 64;

  const int nblk = gridDim.x, cpx = nblk >> 3, orig = blockIdx.x;
  const int wg  = (orig & 7) * cpx + (orig >> 3);
  const int bm  = (wg >> 1) * 128, bn = (wg & 1) * 128;

  GEMM64_BODY(A, Bt, bm, bn, K)

#pragma unroll
  for (int mi = 0; mi < 4; ++mi)
#pragma unroll
    for (int ni = 0; ni < 4; ++ni) {
      int col = bn + wc + ni * 16 + l16;
      float bval = bias[col];
      int row0 = bm + wr + mi * 16 + lg * 4;
#pragma unroll
      for (int i = 0; i < 4; ++i) {
        int row = row0 + i;
        float v = fmaxf(acc[mi][ni][i] + bval, 0.f);
        C[(size_t)row * 256 + col] = (__bf16)((float)R[(size_t)row * 256 + col] + v);
      }
    }
}

// ---------------- small-M GEMM (MLP): fp32 B inline-converted ----------------
template<int EPI, bool OUTF32>
__global__ __launch_bounds__(256) void gemm_kernel(
    const __bf16* __restrict__ A, const float* __restrict__ B,
    const float* __restrict__ bias, const __bf16* __restrict__ R,
    void* __restrict__ Cv, int M, int N, int K)
{
  __shared__ __bf16 sA[64][40];
  __shared__ __bf16 sB[64][40];
  const int tid  = threadIdx.x;
  const int lane = tid & 63;
  const int wv   = tid >> 6;
  const int wr   = (wv >> 1) * 32;
  const int wc   = (wv & 1) * 32;
  const int bm   = blockIdx.x * 64;
  const int bn   = blockIdx.y * 64;
  const int l16  = lane & 15;
  const int lk8  = (lane >> 4) * 8;

  const int a_r = tid >> 2, a_c = (tid & 3) * 8;
  const int b_c = tid & 63, b_k = (tid >> 6) * 8;

  f32x4 acc[2][2] = {};

  for (int k0 = 0; k0 < K; k0 += 32) {
    bf16x8 av = *(const bf16x8*)(A + (size_t)(bm + a_r) * K + k0 + a_c);
    float bvf[8];
#pragma unroll
    for (int j = 0; j < 8; ++j)
      bvf[j] = B[(size_t)(k0 + b_k + j) * N + bn + b_c];
    *(bf16x8*)&sA[a_r][a_c] = av;
    bf16x8 bb;
#pragma unroll
    for (int j = 0; j < 8; ++j) bb[j] = (__bf16)bvf[j];
    *(bf16x8*)&sB[b_c][b_k] = bb;
    __syncthreads();
    bf16x8 af0 = *(const bf16x8*)&sA[wr + l16][lk8];
    bf16x8 af1 = *(const bf16x8*)&sA[wr + 16 + l16][lk8];
    bf16x8 bf0 = *(const bf16x8*)&sB[wc + l16][lk8];
    bf16x8 bf1 = *(const bf16x8*)&sB[wc + 16 + l16][lk8];
    acc[0][0] = __builtin_amdgcn_mfma_f32_16x16x32_bf16(af0, bf0, acc[0][0], 0, 0, 0);
    acc[0][1] = __builtin_amdgcn_mfma_f32_16x16x32_bf16(af0, bf1, acc[0][1], 0, 0, 0);
    acc[1][0] = __builtin_amdgcn_mfma_f32_16x16x32_bf16(af1, bf0, acc[1][0], 0, 0, 0);
    acc[1][1] = __builtin_amdgcn_mfma_f32_16x16x32_bf16(af1, bf1, acc[1][1], 0, 0, 0);
    __syncthreads();
  }

#pragma unroll
  for (int mi = 0; mi < 2; ++mi)
#pragma unroll
    for (int ni = 0; ni < 2; ++ni) {
      int col = bn + wc + ni * 16 + l16;
      float bval = bias[col];
      int row0 = bm + wr + mi * 16 + (lane >> 4) * 4;
#pragma unroll
      for (int i = 0; i < 4; ++i) {
        int row = row0 + i;
        float v = acc[mi][ni][i] + bval;
        if (EPI == 1) v = fmaxf(v, 0.f);
        if (EPI == 2) v = (float)R[(size_t)row * N + col] + fmaxf(v, 0.f);
        if (OUTF32) ((float*)Cv)[(size_t)row * N + col] = v;
        else        ((__bf16*)Cv)[(size_t)row * N + col] = (__bf16)v;
      }
    }
}

// ---------------- fused SAB attention, 32x32 MFMA + in-register P ----------------
// grid 512 = (item*4 + head)*2 + qhalf after XCD swizzle; 8 waves x 32 q-rows.
// K staged via double-buffered global_load_lds (XOR-swizzled source); V reg-gathered
// + transposed into LDS. Swapped QK^T -> P lane-local; permlane32_swap -> PV B-frags.
__global__ __launch_bounds__(512, 4) void attn_sab_kernel(
    __bf16* __restrict__ Q, const __bf16* __restrict__ Kb, const __bf16* __restrict__ Vb)
{
  __shared__ __align__(16) __bf16 sK[2 * 128 * 64];   // [buf][key][64d], 128B rows, swizzled
  __shared__ __align__(16) __bf16 sV[64][136];        // [d][key] transposed (+8 pad)

  const int orig = blockIdx.x;                 // 512 blocks
  const int wg   = (orig & 7) * 64 + (orig >> 3);
  const int qh   = wg & 1;
  const int pair = wg >> 1;                    // 0..255
  const int head = pair & 3;
  const int item = pair >> 2;

  const int tid  = threadIdx.x;
  const int lane = tid & 63;
  const int wv   = tid >> 6;
  const int l32  = lane & 31;
  const int hg   = lane >> 5;
  const size_t base = (size_t)item * (512 * 256) + (size_t)head * 64;
  const int qr0 = qh * 256 + wv * 32;

  // Q B-frags: lane holds Q[q = qr0 + l32][ks*16 + hg*8 + j]
  bf16x8 bq[4];
#pragma unroll
  for (int ks = 0; ks < 4; ++ks)
    bq[ks] = *(const bf16x8*)(Q + base + (size_t)(qr0 + l32) * 256 + ks * 16 + hg * 8);

  f32x16 acco[2] = {};     // O^T strips: lane q=l32, d = ds*32 + (r&3)+8*(r>>2)+4*hg
  float lsum = 0.f;

  const int vch = lane;            // V gather: channel = lane (64 ch)
  const int vk8 = wv * 8;          // 8 keys per wave per pass

#define ISSUE_K(cc, bufv) do {                                                       \
    _Pragma("unroll")                                                                \
    for (int i = 0; i < 2; ++i) {                                                    \
      int rowl = wv * 16 + i * 8 + (lane >> 3);                                      \
      int sl = (lane & 7) ^ (rowl & 7);                                              \
      gload_lds16(Kb + base + (size_t)((cc) * 128 + rowl) * 256 + sl * 8,            \
                  (char*)sK + (bufv) * 16384 + wv * 2048 + i * 1024);                \
    } } while (0)

#define VGATHER(cc) do {                                                             \
    _Pragma("unroll")                                                                \
    for (int p = 0; p < 2; ++p) {                                                    \
      bf16x8 vv;                                                                     \
      _Pragma("unroll")                                                              \
      for (int jj = 0; jj < 8; ++jj)                                                 \
        vv[jj] = Vb[base + (size_t)((cc) * 128 + p * 64 + vk8 + jj) * 256 + vch];    \
      vreg[p] = vv;                                                                  \
    } } while (0)

  bf16x8 vreg[2];
  ISSUE_K(0, 0);
  VGATHER(0);

  for (int c = 0; c < 4; ++c) {
    const int buf = c & 1;
    if (c) __syncthreads();                      // everyone done with sV + old K buf
#pragma unroll
    for (int p = 0; p < 2; ++p)
      *(bf16x8*)&sV[vch][p * 64 + vk8] = vreg[p];
    __syncthreads();                             // sV ready; implicit drain -> K(c) arrived
    if (c < 3) {
      ISSUE_K(c + 1, buf ^ 1);                   // async, overlaps compute below
      VGATHER(c + 1);
    }

    const char* sKb = (const char*)sK + buf * 16384;
#pragma unroll
    for (int st = 0; st < 4; ++st) {
      bf16x8 kf[4];
#pragma unroll
      for (int ks = 0; ks < 4; ++ks) {
        int row = st * 32 + l32;
        int sl = (ks * 2 + hg) ^ (row & 7);
        kf[ks] = *(const bf16x8*)(sKb + row * 128 + sl * 16);
      }
      bf16x8 vf[2][2];
#pragma unroll
      for (int ds = 0; ds < 2; ++ds)
#pragma unroll
        for (int h = 0; h < 2; ++h)
          vf[ds][h] = *(const bf16x8*)&sV[ds * 32 + l32][st * 32 + h * 16 + hg * 8];

      f32x16 s = {};
#pragma unroll
      for (int ks = 0; ks < 4; ++ks)
        s = __builtin_amdgcn_mfma_f32_32x32x16_bf16(kf[ks], bq[ks], s, 0, 0, 0);

      unsigned int pk[8];
      float ls = 0.f;
#pragma unroll
      for (int m = 0; m < 8; ++m) {
        float p0 = __builtin_amdgcn_exp2f(s[2 * m]     * LOG2E_O16);
        float p1 = __builtin_amdgcn_exp2f(s[2 * m + 1] * LOG2E_O16);
        ls += p0 + p1;
        pk[m] = pack2bf(p0, p1);
      }
      lsum += ls;

      pl32swap(pk[0], pk[2]); pl32swap(pk[1], pk[3]);
      pl32swap(pk[4], pk[6]); pl32swap(pk[5], pk[7]);
      u32x4 b0i = {pk[0], pk[1], pk[2], pk[3]};
      u32x4 b1i = {pk[4], pk[5], pk[6], pk[7]};
      bf16x8 pb0 = __builtin_bit_cast(bf16x8, b0i);
      bf16x8 pb1 = __builtin_bit_cast(bf16x8, b1i);

      acco[0] = __builtin_amdgcn_mfma_f32_32x32x16_bf16(vf[0][0], pb0, acco[0], 0, 0, 0);
      acco[0] = __builtin_amdgcn_mfma_f32_32x32x16_bf16(vf[0][1], pb1, acco[0], 0, 0, 0);
      acco[1] = __builtin_amdgcn_mfma_f32_32x32x16_bf16(vf[1][0], pb0, acco[1], 0, 0, 0);
      acco[1] = __builtin_amdgcn_mfma_f32_32x32x16_bf16(vf[1][1], pb1, acco[1], 0, 0, 0);
    }
  }
#undef ISSUE_K
#undef VGATHER

  // epilogue: normalize, residual RMW
  float tot = lsum + __shfl_xor(lsum, 32, 64);
  float inv = 1.0f / tot;
  const size_t qrow = base + (size_t)(qr0 + l32) * 256;
#pragma unroll
  for (int ds = 0; ds < 2; ++ds)
#pragma unroll
    for (int rq = 0; rq < 4; ++rq) {
      int d = ds * 32 + rq * 8 + hg * 4;
      bf16x4 rv = *(const bf16x4*)(Q + qrow + d);
      bf16x4 ov;
#pragma unroll
      for (int i = 0; i < 4; ++i)
        ov[i] = (__bf16)((float)rv[i] + acco[ds][rq * 4 + i] * inv);
      *(bf16x4*)(Q + qrow + d) = ov;
    }
}

// ---------------- PMA q = pma_S @ wq + bq ----------------
__global__ __launch_bounds__(256) void pma_q_kernel(
    const float* __restrict__ S, const float* __restrict__ wq,
    const float* __restrict__ bq, float* __restrict__ qout)
{
  __shared__ float sS[256];
  int t = threadIdx.x;
  sS[t] = S[t];
  __syncthreads();
  float acc = bq[t];
  for (int k = 0; k < 256; ++k) acc += sS[k] * wq[k * 256 + t];
  qout[t] = acc;
}

// ---------------- PMA decode attention ----------------
__global__ __launch_bounds__(256) void pma_attn_kernel(
    const float* __restrict__ qpma, const __bf16* __restrict__ Kb,
    const __bf16* __restrict__ Vb, __bf16* __restrict__ Opma)
{
  __shared__ float sq[256];
  __shared__ float sP[1024];
  __shared__ float red[256];
  __shared__ float sl[2];
  const int item = blockIdx.x;
  const int t = threadIdx.x;
  sq[t] = qpma[t];
  __syncthreads();

#pragma unroll
  for (int rep = 0; rep < 4; ++rep) {
    int task = rep * 256 + t;
    int h = task >> 9, key = task & 511;
    const __bf16* kr = Kb + ((size_t)item * 512 + key) * 256 + h * 128;
    float s = 0.f;
#pragma unroll
    for (int d8 = 0; d8 < 128; d8 += 8) {
      bf16x8 kv = *(const bf16x8*)(kr + d8);
#pragma unroll
      for (int j = 0; j < 8; ++j) s += sq[h * 128 + d8 + j] * (float)kv[j];
    }
    sP[task] = __builtin_amdgcn_exp2f(s * LOG2E_O16);
  }
  __syncthreads();
  {
    int h = t >> 7, kb = t & 127;
    float p = 0.f;
#pragma unroll
    for (int j = 0; j < 4; ++j) p += sP[h * 512 + kb + j * 128];
    red[t] = p;
  }
  __syncthreads();
  if (t < 2) {
    float s = 0.f;
    for (int i = 0; i < 128; ++i) s += red[t * 128 + i];
    sl[t] = 1.f / s;
  }
  __syncthreads();
  {
    int h = t >> 7;
    float acc = 0.f;
    for (int key = 0; key < 512; ++key)
      acc += sP[h * 512 + key] * (float)Vb[((size_t)item * 512 + key) * 256 + t];
    Opma[item * 256 + t] = (__bf16)(sq[t] + acc * sl[h]);
  }
}

// ---------------- launch ----------------
extern "C" void kernel_launch(void* const* d_in, const int* in_sizes, int n_in,
                              void* d_out, int out_size, void* d_ws, size_t ws_size,
                              hipStream_t stream)
{
  const size_t XSZ = (size_t)64 * 512 * 256;
  if (ws_size < 4 * XSZ * sizeof(__bf16) + (4u << 20)) return;

  const float* rep = (const float*)d_in[0];
  const float* GA  = (const float*)d_in[1];

  __bf16* X    = (__bf16*)d_ws;
  __bf16* Qb   = X  + XSZ;
  __bf16* Kb   = Qb + XSZ;
  __bf16* Vb   = Kb + XSZ;
  __bf16* wT   = Vb + XSZ;                 // 10 x 256x256 bf16 (row = out ch, col = k)
  float*  qpma = (float*)(wT + 10 * 65536);
  __bf16* Opma = (__bf16*)(qpma + 256);
  __bf16* O2   = Opma + 64 * 256;
  __bf16* H1   = O2 + 64 * 256;
  __bf16* H2   = H1 + 64 * 512;

  WPtrs wp;
  for (int s = 0; s < 2; ++s)
    for (int j = 0; j < 4; ++j)
      wp.w[s * 4 + j] = (const float*)d_in[2 + s * 8 + j * 2];
  wp.w[8] = (const float*)d_in[21];
  wp.w[9] = (const float*)d_in[23];
  wconv_kernel<<<dim3(16, 10), 256, 0, stream>>>(wp, wT);

  scale_kernel<<<8192, 256, 0, stream>>>(rep, GA, X);

  for (int sab = 0; sab < 2; ++sab) {
    QKV3 a;
    a.Bt[0] = wT + (size_t)(sab * 4 + 0) * 65536;
    a.Bt[1] = wT + (size_t)(sab * 4 + 1) * 65536;
    a.Bt[2] = wT + (size_t)(sab * 4 + 2) * 65536;
    a.bias[0] = (const float*)d_in[2 + sab * 8 + 1];
    a.bias[1] = (const float*)d_in[2 + sab * 8 + 3];
    a.bias[2] = (const float*)d_in[2 + sab * 8 + 5];
    a.out[0] = Qb; a.out[1] = Kb; a.out[2] = Vb;
    gemmqkv_kernel<3><<<1536, 256, 0, stream>>>(X, a, 256);
    attn_sab_kernel<<<512, 512, 0, stream>>>(Qb, Kb, Vb);
    gemm128_kernel<<<512, 256, 0, stream>>>(Qb, wT + (size_t)(sab * 4 + 3) * 65536,
        (const float*)d_in[2 + sab * 8 + 7], Qb, X, 256);
  }

  pma_q_kernel<<<1, 256, 0, stream>>>((const float*)d_in[18], (const float*)d_in[19],
                                      (const float*)d_in[20], qpma);
  {
    QKV3 a;
    a.Bt[0] = wT + (size_t)8 * 65536;
    a.Bt[1] = wT + (size_t)9 * 65536;
    a.Bt[2] = wT;  // unused
    a.bias[0] = (const float*)d_in[22];
    a.bias[1] = (const float*)d_in[24];
    a.bias[2] = (const float*)d_in[22];  // unused
    a.out[0] = Kb; a.out[1] = Vb; a.out[2] = Kb;  // slot 2 unused
    gemmqkv_kernel<2><<<1024, 256, 0, stream>>>(X, a, 256);
  }
  pma_attn_kernel<<<64, 256, 0, stream>>>(qpma, Kb, Vb, Opma);
  gemm_kernel<2, false><<<dim3(1, 4), 256, 0, stream>>>(Opma, (const float*)d_in[25],
      (const float*)d_in[26], Opma, O2, 64, 256, 256);
  gemm_kernel<1, false><<<dim3(1, 8), 256, 0, stream>>>(O2, (const float*)d_in[27],
      (const float*)d_in[28], nullptr, H1, 64, 512, 256);
  gemm_kernel<1, false><<<dim3(1, 8), 256, 0, stream>>>(H1, (const float*)d_in[29],
      (const float*)d_in[30], nullptr, H2, 64, 512, 512);
  gemm_kernel<0, true><<<dim3(1, 4), 256, 0, stream>>>(H2, (const float*)d_in[31],
      (const float*)d_in[32], nullptr, (float*)d_out, 64, 256, 512);
}

// Round 6
// 250.218 us; speedup vs baseline: 1.1016x; 1.1016x over previous
//
#include <hip/hip_runtime.h>
#include <hip/hip_bf16.h>

typedef __attribute__((ext_vector_type(4)))  float  f32x4;
typedef __attribute__((ext_vector_type(16))) float  f32x16;
typedef __attribute__((ext_vector_type(8)))  __bf16 bf16x8;
typedef __attribute__((ext_vector_type(4)))  __bf16 bf16x4;
typedef unsigned int u32x2 __attribute__((ext_vector_type(2)));
typedef unsigned int u32x4 __attribute__((ext_vector_type(4)));

#define LOG2E_O16 0.09016844005556021f  // log2(e)/16  (scale = 1/sqrt(256))

__device__ __forceinline__ void gload_lds16(const void* g, void* l) {
  __builtin_amdgcn_global_load_lds(
      (const __attribute__((address_space(1))) void*)g,
      (__attribute__((address_space(3))) void*)l, 16, 0, 0);
}

__device__ __forceinline__ void pl32swap(unsigned int& a, unsigned int& b) {
  u32x2 r = __builtin_amdgcn_permlane32_swap(a, b, false, false);
  a = r[0]; b = r[1];
}

__device__ __forceinline__ unsigned int pack2bf(float a, float b) {
  unsigned short ua = __builtin_bit_cast(unsigned short, (__bf16)a);
  unsigned short ub = __builtin_bit_cast(unsigned short, (__bf16)b);
  return (unsigned int)ua | ((unsigned int)ub << 16);
}

// ---------------- X = GA[g,n] * rep_R, fp32 -> bf16 ----------------
__global__ __launch_bounds__(256) void scale_kernel(
    const float* __restrict__ rep, const float* __restrict__ GA, __bf16* __restrict__ X)
{
  size_t i = (size_t)blockIdx.x * 256 + threadIdx.x;
  size_t e = i * 4;
  f32x4 r = *(const f32x4*)(rep + e);
  int dn = (int)(e >> 8);
  int n  = dn & 511;
  int g  = (dn >> 9) & 15;
  float ga = GA[g * 512 + n];
  bf16x4 o;
  o[0] = (__bf16)(r[0] * ga); o[1] = (__bf16)(r[1] * ga);
  o[2] = (__bf16)(r[2] * ga); o[3] = (__bf16)(r[3] * ga);
  *(bf16x4*)(X + e) = o;
}

// ---------------- weight convert: ten 256x256 fp32 w[K][N] -> bf16 wT[N][K] ----------------
struct WPtrs { const float* w[10]; };
__global__ __launch_bounds__(256) void wconv_kernel(WPtrs ws, __bf16* __restrict__ out)
{
  __shared__ float t[64][65];
  const float* w = ws.w[blockIdx.y];
  __bf16* o = out + (size_t)blockIdx.y * 65536;
  const int tr = (blockIdx.x & 3) * 64, tc = (blockIdx.x >> 2) * 64;
  const int r4 = threadIdx.x >> 6, c = threadIdx.x & 63;
#pragma unroll
  for (int p = 0; p < 16; ++p) {
    int row = p * 4 + r4;
    t[row][c] = w[(size_t)(tr + row) * 256 + tc + c];
  }
  __syncthreads();
#pragma unroll
  for (int p = 0; p < 16; ++p) {
    int row = p * 4 + r4;
    o[(size_t)(tc + row) * 256 + tr + c] = (__bf16)t[c][row];
  }
}

// ======== 2-phase pipelined BK=64 tile body (128x128 tile, 4 waves, dbuf LDS) ========
// Stage(t+1) issued BEFORE compute(t); single vmcnt(0)+raw-barrier per K-step.
#define STAGE_T(A_, B_, bmv, bnv, Kv, tt, bb) do {                                 \
    _Pragma("unroll")                                                              \
    for (int r = 0; r < 4; ++r) {                                                  \
      int rowl = r * 32 + (tid >> 3);                                              \
      int sl = (tid & 7) ^ (rowl & 7);                                             \
      gload_lds16((const char*)((A_) + (size_t)((bmv) + rowl) * (Kv) + (tt) * 64) + sl * 16, \
                  (char*)sA + (bb) * 16384 + r * 4096 + wv * 1024);                \
      gload_lds16((const char*)((B_) + (size_t)((bnv) + rowl) * (Kv) + (tt) * 64) + sl * 16, \
                  (char*)sB + (bb) * 16384 + r * 4096 + wv * 1024);                \
    } } while (0)

#define GEMM64_PIPE(A_, B_, bmv, bnv, Kv)                                          \
  f32x4 acc[4][4] = {};                                                            \
  const int nt = (Kv) >> 6;                                                        \
  STAGE_T(A_, B_, bmv, bnv, Kv, 0, 0);                                             \
  asm volatile("s_waitcnt vmcnt(0)" ::: "memory");                                 \
  __builtin_amdgcn_s_barrier();                                                    \
  for (int t = 0; t < nt; ++t) {                                                   \
    if (t + 1 < nt) STAGE_T(A_, B_, bmv, bnv, Kv, t + 1, (t + 1) & 1);             \
    const char* bA = (const char*)sA + (t & 1) * 16384;                            \
    const char* bB = (const char*)sB + (t & 1) * 16384;                            \
    bf16x8 af[4][2], bfr[4][2];                                                    \
    _Pragma("unroll")                                                              \
    for (int mi = 0; mi < 4; ++mi) {                                               \
      int row = wr + mi * 16 + l16;                                                \
      _Pragma("unroll")                                                            \
      for (int kk = 0; kk < 2; ++kk) {                                             \
        int sl = (kk * 4 + lg) ^ (row & 7);                                        \
        af[mi][kk] = *(const bf16x8*)(bA + row * 128 + sl * 16);                   \
      }                                                                            \
    }                                                                              \
    _Pragma("unroll")                                                              \
    for (int ni = 0; ni < 4; ++ni) {                                               \
      int row = wc + ni * 16 + l16;                                                \
      _Pragma("unroll")                                                            \
      for (int kk = 0; kk < 2; ++kk) {                                             \
        int sl = (kk * 4 + lg) ^ (row & 7);                                        \
        bfr[ni][kk] = *(const bf16x8*)(bB + row * 128 + sl * 16);                  \
      }                                                                            \
    }                                                                              \
    _Pragma("unroll")                                                              \
    for (int kk = 0; kk < 2; ++kk)                                                 \
      _Pragma("unroll")                                                            \
      for (int mi = 0; mi < 4; ++mi)                                               \
        _Pragma("unroll")                                                          \
        for (int ni = 0; ni < 4; ++ni)                                             \
          acc[mi][ni] = __builtin_amdgcn_mfma_f32_16x16x32_bf16(                   \
              af[mi][kk], bfr[ni][kk], acc[mi][ni], 0, 0, 0);                      \
    asm volatile("s_waitcnt vmcnt(0)" ::: "memory");                               \
    __builtin_amdgcn_s_barrier();                                                  \
  }

// ---------------- fused multi-output GEMM: out[j] = A @ Bt[j]^T + bias[j] ----------------
struct QKV3 {
  const __bf16* Bt[3];
  const float* bias[3];
  __bf16* out[3];
};

template<int NW>
__global__ __launch_bounds__(256) void gemmqkv_kernel(
    const __bf16* __restrict__ A, QKV3 args, int K)
{
  __shared__ __align__(16) __bf16 sA[2 * 128 * 64];
  __shared__ __align__(16) __bf16 sB[2 * 128 * 64];
  const int tid = threadIdx.x, lane = tid & 63, wv = tid >> 6;
  const int l16 = lane & 15, lg = lane >> 4;
  const int wr = (wv >> 1) * 64, wc = (wv & 1) * 64;

  const int nblk = gridDim.x, cpx = nblk >> 3, orig = blockIdx.x;
  const int wg  = (orig & 7) * cpx + (orig >> 3);       // bijective XCD swizzle
  const int r_  = wg / (2 * NW), rem = wg % (2 * NW);
  const int j   = rem >> 1;
  const int bm  = r_ * 128, bn = (rem & 1) * 128;
  const __bf16* __restrict__ Bt = args.Bt[j];

  GEMM64_PIPE(A, Bt, bm, bn, K)

  const float* bias = args.bias[j];
  __bf16* C = args.out[j];
#pragma unroll
  for (int mi = 0; mi < 4; ++mi)
#pragma unroll
    for (int ni = 0; ni < 4; ++ni) {
      int col = bn + wc + ni * 16 + l16;
      float bval = bias[col];
      int row0 = bm + wr + mi * 16 + lg * 4;
#pragma unroll
      for (int i = 0; i < 4; ++i)
        C[(size_t)(row0 + i) * 256 + col] = (__bf16)(acc[mi][ni][i] + bval);
    }
}

// ---------------- O-proj GEMM: C = R + relu(A @ Bt^T + bias) ----------------
__global__ __launch_bounds__(256) void gemm128_kernel(
    const __bf16* __restrict__ A, const __bf16* __restrict__ Bt,
    const float* __restrict__ bias, const __bf16* __restrict__ R,
    __bf16* __restrict__ C, int K)
{
  __shared__ __align__(16) __bf16 sA[2 * 128 * 64];
  __shared__ __align__(16) __bf16 sB[2 * 128 * 64];
  const int tid = threadIdx.x, lane = tid & 63, wv = tid >> 6;
  const int l16 = lane & 15, lg = lane >> 4;
  const int wr = (wv >> 1) * 64, wc = (wv & 1) * 64;

  const int nblk = gridDim.x, cpx = nblk >> 3, orig = blockIdx.x;
  const int wg  = (orig & 7) * cpx + (orig >> 3);
  const int bm  = (wg >> 1) * 128, bn = (wg & 1) * 128;

  GEMM64_PIPE(A, Bt, bm, bn, K)

#pragma unroll
  for (int mi = 0; mi < 4; ++mi)
#pragma unroll
    for (int ni = 0; ni < 4; ++ni) {
      int col = bn + wc + ni * 16 + l16;
      float bval = bias[col];
      int row0 = bm + wr + mi * 16 + lg * 4;
#pragma unroll
      for (int i = 0; i < 4; ++i) {
        int row = row0 + i;
        float v = fmaxf(acc[mi][ni][i] + bval, 0.f);
        C[(size_t)row * 256 + col] = (__bf16)((float)R[(size_t)row * 256 + col] + v);
      }
    }
}

// ---------------- small-M GEMM (MLP): fp32 B inline-converted ----------------
template<int EPI, bool OUTF32>
__global__ __launch_bounds__(256) void gemm_kernel(
    const __bf16* __restrict__ A, const float* __restrict__ B,
    const float* __restrict__ bias, const __bf16* __restrict__ R,
    void* __restrict__ Cv, int M, int N, int K)
{
  __shared__ __bf16 sA[64][40];
  __shared__ __bf16 sB[64][40];
  const int tid  = threadIdx.x;
  const int lane = tid & 63;
  const int wv   = tid >> 6;
  const int wr   = (wv >> 1) * 32;
  const int wc   = (wv & 1) * 32;
  const int bm   = blockIdx.x * 64;
  const int bn   = blockIdx.y * 64;
  const int l16  = lane & 15;
  const int lk8  = (lane >> 4) * 8;

  const int a_r = tid >> 2, a_c = (tid & 3) * 8;
  const int b_c = tid & 63, b_k = (tid >> 6) * 8;

  f32x4 acc[2][2] = {};

  for (int k0 = 0; k0 < K; k0 += 32) {
    bf16x8 av = *(const bf16x8*)(A + (size_t)(bm + a_r) * K + k0 + a_c);
    float bvf[8];
#pragma unroll
    for (int j = 0; j < 8; ++j)
      bvf[j] = B[(size_t)(k0 + b_k + j) * N + bn + b_c];
    *(bf16x8*)&sA[a_r][a_c] = av;
    bf16x8 bb;
#pragma unroll
    for (int j = 0; j < 8; ++j) bb[j] = (__bf16)bvf[j];
    *(bf16x8*)&sB[b_c][b_k] = bb;
    __syncthreads();
    bf16x8 af0 = *(const bf16x8*)&sA[wr + l16][lk8];
    bf16x8 af1 = *(const bf16x8*)&sA[wr + 16 + l16][lk8];
    bf16x8 bf0 = *(const bf16x8*)&sB[wc + l16][lk8];
    bf16x8 bf1 = *(const bf16x8*)&sB[wc + 16 + l16][lk8];
    acc[0][0] = __builtin_amdgcn_mfma_f32_16x16x32_bf16(af0, bf0, acc[0][0], 0, 0, 0);
    acc[0][1] = __builtin_amdgcn_mfma_f32_16x16x32_bf16(af0, bf1, acc[0][1], 0, 0, 0);
    acc[1][0] = __builtin_amdgcn_mfma_f32_16x16x32_bf16(af1, bf0, acc[1][0], 0, 0, 0);
    acc[1][1] = __builtin_amdgcn_mfma_f32_16x16x32_bf16(af1, bf1, acc[1][1], 0, 0, 0);
    __syncthreads();
  }

#pragma unroll
  for (int mi = 0; mi < 2; ++mi)
#pragma unroll
    for (int ni = 0; ni < 2; ++ni) {
      int col = bn + wc + ni * 16 + l16;
      float bval = bias[col];
      int row0 = bm + wr + mi * 16 + (lane >> 4) * 4;
#pragma unroll
      for (int i = 0; i < 4; ++i) {
        int row = row0 + i;
        float v = acc[mi][ni][i] + bval;
        if (EPI == 1) v = fmaxf(v, 0.f);
        if (EPI == 2) v = (float)R[(size_t)row * N + col] + fmaxf(v, 0.f);
        if (OUTF32) ((float*)Cv)[(size_t)row * N + col] = v;
        else        ((__bf16*)Cv)[(size_t)row * N + col] = (__bf16)v;
      }
    }
}

// ---------------- fused SAB attention, 32x32 MFMA + in-register P ----------------
// grid 512 = (item*4 + head)*2 + qhalf after XCD swizzle; 8 waves x 32 q-rows.
// Epilogue stages O through LDS (reusing sK) so the Q RMW is sector-coalesced.
__global__ __launch_bounds__(512, 4) void attn_sab_kernel(
    __bf16* __restrict__ Q, const __bf16* __restrict__ Kb, const __bf16* __restrict__ Vb)
{
  __shared__ __align__(16) __bf16 sK[2 * 128 * 64];   // [buf][key][64d]; reused as f32 sO
  __shared__ __align__(16) __bf16 sV[64][136];        // [d][key] transposed (+8 pad)

  const int orig = blockIdx.x;                 // 512 blocks
  const int wg   = (orig & 7) * 64 + (orig >> 3);
  const int qh   = wg & 1;
  const int pair = wg >> 1;                    // 0..255
  const int head = pair & 3;
  const int item = pair >> 2;

  const int tid  = threadIdx.x;
  const int lane = tid & 63;
  const int wv   = tid >> 6;
  const int l32  = lane & 31;
  const int hg   = lane >> 5;
  const size_t base = (size_t)item * (512 * 256) + (size_t)head * 64;
  const int qblk = qh * 256;
  const int qr0 = qblk + wv * 32;

  // Q B-frags: lane holds Q[q = qr0 + l32][ks*16 + hg*8 + j]
  bf16x8 bq[4];
#pragma unroll
  for (int ks = 0; ks < 4; ++ks)
    bq[ks] = *(const bf16x8*)(Q + base + (size_t)(qr0 + l32) * 256 + ks * 16 + hg * 8);

  f32x16 acco[2] = {};     // O^T strips: lane q=l32, d = ds*32 + (r&3)+8*(r>>2)+4*hg
  float lsum = 0.f;

  const int vch = lane;
  const int vk8 = wv * 8;

#define ISSUE_K(cc, bufv) do {                                                       \
    _Pragma("unroll")                                                                \
    for (int i = 0; i < 2; ++i) {                                                    \
      int rowl = wv * 16 + i * 8 + (lane >> 3);                                      \
      int sl = (lane & 7) ^ (rowl & 7);                                              \
      gload_lds16(Kb + base + (size_t)((cc) * 128 + rowl) * 256 + sl * 8,            \
                  (char*)sK + (bufv) * 16384 + wv * 2048 + i * 1024);                \
    } } while (0)

#define VGATHER(cc) do {                                                             \
    _Pragma("unroll")                                                                \
    for (int p = 0; p < 2; ++p) {                                                    \
      bf16x8 vv;                                                                     \
      _Pragma("unroll")                                                              \
      for (int jj = 0; jj < 8; ++jj)                                                 \
        vv[jj] = Vb[base + (size_t)((cc) * 128 + p * 64 + vk8 + jj) * 256 + vch];    \
      vreg[p] = vv;                                                                  \
    } } while (0)

  bf16x8 vreg[2];
  ISSUE_K(0, 0);
  VGATHER(0);

  for (int c = 0; c < 4; ++c) {
    const int buf = c & 1;
    if (c) __syncthreads();
#pragma unroll
    for (int p = 0; p < 2; ++p)
      *(bf16x8*)&sV[vch][p * 64 + vk8] = vreg[p];
    __syncthreads();
    if (c < 3) {
      ISSUE_K(c + 1, buf ^ 1);
      VGATHER(c + 1);
    }

    const char* sKb = (const char*)sK + buf * 16384;
#pragma unroll
    for (int st = 0; st < 4; ++st) {
      bf16x8 kf[4];
#pragma unroll
      for (int ks = 0; ks < 4; ++ks) {
        int row = st * 32 + l32;
        int sl = (ks * 2 + hg) ^ (row & 7);
        kf[ks] = *(const bf16x8*)(sKb + row * 128 + sl * 16);
      }
      bf16x8 vf[2][2];
#pragma unroll
      for (int ds = 0; ds < 2; ++ds)
#pragma unroll
        for (int h = 0; h < 2; ++h)
          vf[ds][h] = *(const bf16x8*)&sV[ds * 32 + l32][st * 32 + h * 16 + hg * 8];

      f32x16 s = {};
#pragma unroll
      for (int ks = 0; ks < 4; ++ks)
        s = __builtin_amdgcn_mfma_f32_32x32x16_bf16(kf[ks], bq[ks], s, 0, 0, 0);

      unsigned int pk[8];
      float ls = 0.f;
#pragma unroll
      for (int m = 0; m < 8; ++m) {
        float p0 = __builtin_amdgcn_exp2f(s[2 * m]     * LOG2E_O16);
        float p1 = __builtin_amdgcn_exp2f(s[2 * m + 1] * LOG2E_O16);
        ls += p0 + p1;
        pk[m] = pack2bf(p0, p1);
      }
      lsum += ls;

      pl32swap(pk[0], pk[2]); pl32swap(pk[1], pk[3]);
      pl32swap(pk[4], pk[6]); pl32swap(pk[5], pk[7]);
      u32x4 b0i = {pk[0], pk[1], pk[2], pk[3]};
      u32x4 b1i = {pk[4], pk[5], pk[6], pk[7]};
      bf16x8 pb0 = __builtin_bit_cast(bf16x8, b0i);
      bf16x8 pb1 = __builtin_bit_cast(bf16x8, b1i);

      acco[0] = __builtin_amdgcn_mfma_f32_32x32x16_bf16(vf[0][0], pb0, acco[0], 0, 0, 0);
      acco[0] = __builtin_amdgcn_mfma_f32_32x32x16_bf16(vf[0][1], pb1, acco[0], 0, 0, 0);
      acco[1] = __builtin_amdgcn_mfma_f32_32x32x16_bf16(vf[1][0], pb0, acco[1], 0, 0, 0);
      acco[1] = __builtin_amdgcn_mfma_f32_32x32x16_bf16(vf[1][1], pb1, acco[1], 0, 0, 0);
    }
  }
#undef ISSUE_K
#undef VGATHER

  // ---- epilogue: LDS-staged, sector-coalesced Q RMW ----
  float tot = lsum + __shfl_xor(lsum, 32, 64);
  float inv = 1.0f / tot;
  float* sO = (float*)sK;                       // 8 waves x 32q x 32d f32 = 32 KB
  const int erow = tid >> 1;                    // 0..255 (row within block)
  const int eseg = tid & 1;                     // 16-channel segment
  const int ewv  = erow >> 5, eq = erow & 31;
  const int esw  = (eq & 7) << 2;

#pragma unroll
  for (int ds = 0; ds < 2; ++ds) {
    __syncthreads();                            // sK free / prev pass read done
    float* w = sO + wv * 1024 + l32 * 32;
    const int wsw = (l32 & 7) << 2;
#pragma unroll
    for (int rq = 0; rq < 4; ++rq) {
      int d0 = rq * 8 + hg * 4;
      f32x4 v4;
#pragma unroll
      for (int i = 0; i < 4; ++i) v4[i] = acco[ds][rq * 4 + i] * inv;
      *(f32x4*)(w + (d0 ^ wsw)) = v4;
    }
    __syncthreads();
    const float* rd = sO + ewv * 1024 + eq * 32;
    f32x4 r0 = *(const f32x4*)(rd + ((eseg * 16 + 0)  ^ esw));
    f32x4 r1 = *(const f32x4*)(rd + ((eseg * 16 + 4)  ^ esw));
    f32x4 r2 = *(const f32x4*)(rd + ((eseg * 16 + 8)  ^ esw));
    f32x4 r3 = *(const f32x4*)(rd + ((eseg * 16 + 12) ^ esw));
    __bf16* gp = Q + base + (size_t)(qblk + erow) * 256 + ds * 32 + eseg * 16;
    bf16x8 q0 = *(const bf16x8*)gp;
    bf16x8 q1 = *(const bf16x8*)(gp + 8);
    bf16x8 o0, o1;
#pragma unroll
    for (int i = 0; i < 4; ++i) {
      o0[i]     = (__bf16)((float)q0[i]     + r0[i]);
      o0[i + 4] = (__bf16)((float)q0[i + 4] + r1[i]);
      o1[i]     = (__bf16)((float)q1[i]     + r2[i]);
      o1[i + 4] = (__bf16)((float)q1[i + 4] + r3[i]);
    }
    *(bf16x8*)gp = o0;
    *(bf16x8*)(gp + 8) = o1;
  }
}

// ---------------- PMA decode attention (q computed in-kernel) ----------------
__global__ __launch_bounds__(256) void pma_attn_kernel(
    const float* __restrict__ S, const float* __restrict__ wq,
    const float* __restrict__ bq, const __bf16* __restrict__ Kb,
    const __bf16* __restrict__ Vb, __bf16* __restrict__ Opma)
{
  __shared__ float sS[256];
  __shared__ float sq[256];
  __shared__ float sP[1024];
  __shared__ float red[256];
  __shared__ float sl[2];
  const int item = blockIdx.x;
  const int t = threadIdx.x;
  sS[t] = S[t];
  __syncthreads();
  {
    float acc = bq[t];
#pragma unroll 8
    for (int k = 0; k < 256; ++k) acc += sS[k] * wq[k * 256 + t];
    sq[t] = acc;
  }
  __syncthreads();

#pragma unroll
  for (int rep = 0; rep < 4; ++rep) {
    int task = rep * 256 + t;
    int h = task >> 9, key = task & 511;
    const __bf16* kr = Kb + ((size_t)item * 512 + key) * 256 + h * 128;
    float s = 0.f;
#pragma unroll
    for (int d8 = 0; d8 < 128; d8 += 8) {
      bf16x8 kv = *(const bf16x8*)(kr + d8);
#pragma unroll
      for (int j = 0; j < 8; ++j) s += sq[h * 128 + d8 + j] * (float)kv[j];
    }
    sP[task] = __builtin_amdgcn_exp2f(s * LOG2E_O16);
  }
  __syncthreads();
  {
    int h = t >> 7, kb = t & 127;
    float p = 0.f;
#pragma unroll
    for (int j = 0; j < 4; ++j) p += sP[h * 512 + kb + j * 128];
    red[t] = p;
  }
  __syncthreads();
  if (t < 2) {
    float s = 0.f;
    for (int i = 0; i < 128; ++i) s += red[t * 128 + i];
    sl[t] = 1.f / s;
  }
  __syncthreads();
  {
    int h = t >> 7;
    float acc = 0.f;
    for (int key = 0; key < 512; ++key)
      acc += sP[h * 512 + key] * (float)Vb[((size_t)item * 512 + key) * 256 + t];
    Opma[item * 256 + t] = (__bf16)(sq[t] + acc * sl[h]);
  }
}

// ---------------- launch ----------------
extern "C" void kernel_launch(void* const* d_in, const int* in_sizes, int n_in,
                              void* d_out, int out_size, void* d_ws, size_t ws_size,
                              hipStream_t stream)
{
  const size_t XSZ = (size_t)64 * 512 * 256;
  if (ws_size < 4 * XSZ * sizeof(__bf16) + (4u << 20)) return;

  const float* rep = (const float*)d_in[0];
  const float* GA  = (const float*)d_in[1];

  __bf16* X    = (__bf16*)d_ws;
  __bf16* Qb   = X  + XSZ;
  __bf16* Kb   = Qb + XSZ;
  __bf16* Vb   = Kb + XSZ;
  __bf16* wT   = Vb + XSZ;                 // 10 x 256x256 bf16 (row = out ch, col = k)
  __bf16* Opma = wT + 10 * 65536;
  __bf16* O2   = Opma + 64 * 256;
  __bf16* H1   = O2 + 64 * 256;
  __bf16* H2   = H1 + 64 * 512;

  WPtrs wp;
  for (int s = 0; s < 2; ++s)
    for (int j = 0; j < 4; ++j)
      wp.w[s * 4 + j] = (const float*)d_in[2 + s * 8 + j * 2];
  wp.w[8] = (const float*)d_in[21];
  wp.w[9] = (const float*)d_in[23];
  wconv_kernel<<<dim3(16, 10), 256, 0, stream>>>(wp, wT);

  scale_kernel<<<8192, 256, 0, stream>>>(rep, GA, X);

  for (int sab = 0; sab < 2; ++sab) {
    QKV3 a;
    a.Bt[0] = wT + (size_t)(sab * 4 + 0) * 65536;
    a.Bt[1] = wT + (size_t)(sab * 4 + 1) * 65536;
    a.Bt[2] = wT + (size_t)(sab * 4 + 2) * 65536;
    a.bias[0] = (const float*)d_in[2 + sab * 8 + 1];
    a.bias[1] = (const float*)d_in[2 + sab * 8 + 3];
    a.bias[2] = (const float*)d_in[2 + sab * 8 + 5];
    a.out[0] = Qb; a.out[1] = Kb; a.out[2] = Vb;
    gemmqkv_kernel<3><<<1536, 256, 0, stream>>>(X, a, 256);
    attn_sab_kernel<<<512, 512, 0, stream>>>(Qb, Kb, Vb);
    gemm128_kernel<<<512, 256, 0, stream>>>(Qb, wT + (size_t)(sab * 4 + 3) * 65536,
        (const float*)d_in[2 + sab * 8 + 7], Qb, X, 256);
  }

  {
    QKV3 a;
    a.Bt[0] = wT + (size_t)8 * 65536;
    a.Bt[1] = wT + (size_t)9 * 65536;
    a.Bt[2] = wT;  // unused
    a.bias[0] = (const float*)d_in[22];
    a.bias[1] = (const float*)d_in[24];
    a.bias[2] = (const float*)d_in[22];  // unused
    a.out[0] = Kb; a.out[1] = Vb; a.out[2] = Kb;  // slot 2 unused
    gemmqkv_kernel<2><<<1024, 256, 0, stream>>>(X, a, 256);
  }
  pma_attn_kernel<<<64, 256, 0, stream>>>((const float*)d_in[18], (const float*)d_in[19],
      (const float*)d_in[20], Kb, Vb, Opma);
  gemm_kernel<2, false><<<dim3(1, 4), 256, 0, stream>>>(Opma, (const float*)d_in[25],
      (const float*)d_in[26], Opma, O2, 64, 256, 256);
  gemm_kernel<1, false><<<dim3(1, 8), 256, 0, stream>>>(O2, (const float*)d_in[27],
      (const float*)d_in[28], nullptr, H1, 64, 512, 256);
  gemm_kernel<1, false><<<dim3(1, 8), 256, 0, stream>>>(H1, (const float*)d_in[29],
      (const float*)d_in[30], nullptr, H2, 64, 512, 512);
  gemm_kernel<0, true><<<dim3(1, 4), 256, 0, stream>>>(H2, (const float*)d_in[31],
      (const float*)d_in[32], nullptr, (float*)d_out, 64, 256, 512);
}